// Round 1
// 96.186 us; speedup vs baseline: 1.7853x; 1.7853x over previous
//
#include <hip/hip_runtime.h>
#include <hip/hip_bf16.h>
#include <cstdint>
#include <cstddef>

#define TOKENS 16384
#define DMODEL 4096
#define NEXP   64
#define KSPLIT 2
#define KSPAN  (DMODEL / KSPLIT)    // 2048 k per wave
#define NKC    (KSPAN / 16)         // 128 k-chunks of 16

typedef __attribute__((ext_vector_type(8)))  short bf16x8;   // 8 bf16 = 4 VGPRs
typedef __attribute__((ext_vector_type(16))) float f32x16;   // 32x32 acc

// 8 fp32 -> hi/lo bf16 fragments (RNE hi, exact fp32 residual -> lo; ~2^-17 rel)
__device__ __forceinline__ void cvt_hilo8(const float f[8], bf16x8* hi, bf16x8* lo) {
  union { __hip_bfloat16 b; unsigned short u; } cv;
  bf16x8 hv, lv;
#pragma unroll
  for (int j = 0; j < 8; ++j) {
    __hip_bfloat16 hb = __float2bfloat16(f[j]);
    cv.b = hb; hv[j] = (short)cv.u;
    float r = f[j] - __bfloat162float(hb);          // exact
    cv.b = __float2bfloat16(r); lv[j] = (short)cv.u;
  }
  *hi = hv; *lo = lv;
}

// ---------------- kernel 1: W -> pre-fragmented bf16 hi/lo ----------------
// slot[(kc*2+et)*64 + l] (16B) = bf16 of W[et*32 + (l&31)][kc*16 + (l>>5)*8 + j], j=0..7
__global__ __launch_bounds__(256)
void prep_W(const float* __restrict__ W, uint4* __restrict__ wh, uint4* __restrict__ wl) {
  const int tid = blockIdx.x * 256 + threadIdx.x;   // 32768 threads total
  const int l  = tid & 63;
  const int et = (tid >> 6) & 1;
  const int kc = tid >> 7;                           // 0..255
  const int e  = et * 32 + (l & 31);
  const int k  = kc * 16 + (l >> 5) * 8;
  const float* src = W + (size_t)e * DMODEL + k;
  float f[8];
#pragma unroll
  for (int j = 0; j < 8; ++j) f[j] = src[j];
  bf16x8 hi, lo;
  cvt_hilo8(f, &hi, &lo);
  const int slot = (kc * 2 + et) * 64 + l;
  wh[slot] = __builtin_bit_cast(uint4, hi);
  wl[slot] = __builtin_bit_cast(uint4, lo);
}

// ---------------- kernel 2: MFMA GEMM, no LDS, no barriers ----------------
// grid 1024 x 64thr: wave = 32 tokens x 64 experts x half of K.
__global__ __launch_bounds__(64)
void gemm_mfma(const float* __restrict__ x, const uint4* __restrict__ wh,
               const uint4* __restrict__ wl, float* __restrict__ part) {
  const int l   = threadIdx.x;
  const int wid = blockIdx.x;               // 0..1023
  const int t0  = (wid & 511) * 32;
  const int ks  = wid >> 9;                 // k-half
  const int row = l & 31, g = l >> 5;

  const float* xp  = x  + (size_t)(t0 + row) * DMODEL + ks * KSPAN + g * 8;
  const uint4* whp = wh + (size_t)ks * (NKC * 128) + l;   // 128 uint4 per kc (2 et-tiles)
  const uint4* wlp = wl + (size_t)ks * (NKC * 128) + l;

  f32x16 acc0, acc1;
#pragma unroll
  for (int i = 0; i < 16; ++i) { acc0[i] = 0.f; acc1[i] = 0.f; }

  // prefetch iter 0
  float4 a0 = *(const float4*)(xp);
  float4 a1 = *(const float4*)(xp + 4);
  uint4 bh0 = whp[0], bh1 = whp[64];
  uint4 bl0 = wlp[0], bl1 = wlp[64];

  for (int kc = 0; kc < NKC; ++kc) {
    float4 na0 = a0, na1 = a1; uint4 nh0 = bh0, nh1 = bh1, nl0 = bl0, nl1 = bl1;
    if (kc + 1 < NKC) {                      // issue next-iter loads first (1-deep prefetch)
      const float* xn = xp + (kc + 1) * 16;
      na0 = *(const float4*)(xn);
      na1 = *(const float4*)(xn + 4);
      const uint4* whn = whp + (kc + 1) * 128;
      const uint4* wln = wlp + (kc + 1) * 128;
      nh0 = whn[0]; nh1 = whn[64];
      nl0 = wln[0]; nl1 = wln[64];
    }
    float f[8] = {a0.x, a0.y, a0.z, a0.w, a1.x, a1.y, a1.z, a1.w};
    bf16x8 ah, al;
    cvt_hilo8(f, &ah, &al);
    bf16x8 vh0 = __builtin_bit_cast(bf16x8, bh0);
    bf16x8 vh1 = __builtin_bit_cast(bf16x8, bh1);
    bf16x8 vl0 = __builtin_bit_cast(bf16x8, bl0);
    bf16x8 vl1 = __builtin_bit_cast(bf16x8, bl1);
    // fp32-emulated: hi*hi + hi*lo + lo*hi (lo*lo ~2^-18, dropped)
    acc0 = __builtin_amdgcn_mfma_f32_32x32x16_bf16(ah, vh0, acc0, 0, 0, 0);
    acc1 = __builtin_amdgcn_mfma_f32_32x32x16_bf16(ah, vh1, acc1, 0, 0, 0);
    acc0 = __builtin_amdgcn_mfma_f32_32x32x16_bf16(ah, vl0, acc0, 0, 0, 0);
    acc1 = __builtin_amdgcn_mfma_f32_32x32x16_bf16(ah, vl1, acc1, 0, 0, 0);
    acc0 = __builtin_amdgcn_mfma_f32_32x32x16_bf16(al, vh0, acc0, 0, 0, 0);
    acc1 = __builtin_amdgcn_mfma_f32_32x32x16_bf16(al, vh1, acc1, 0, 0, 0);
    a0 = na0; a1 = na1; bh0 = nh0; bh1 = nh1; bl0 = nl0; bl1 = nl1;
  }

  // C/D layout (verified m74/m101): col = lane&31, row = (r&3) + 8*(r>>2) + 4*(lane>>5)
  float* p = part + ((size_t)ks * TOKENS + t0) * NEXP;
#pragma unroll
  for (int r = 0; r < 16; ++r) {
    const int rr = (r & 3) + 8 * (r >> 2) + 4 * g;
    p[(size_t)rr * NEXP + row]      = acc0[r];
    p[(size_t)rr * NEXP + 32 + row] = acc1[r];
  }
}

// ---------------- kernel 3: reduce halves + bias, top-2, softmax (unchanged) ----------------
__global__ __launch_bounds__(256)
void topk_softmax(const float* __restrict__ part, const float* __restrict__ b,
                  float* __restrict__ out) {
  const int tid = threadIdx.x;
  const int lane = tid & 63;
  const int wv = tid >> 6;
  const int t = blockIdx.x * 4 + wv;

  float v = part[(size_t)t * NEXP + lane]
          + part[(size_t)(TOKENS + t) * NEXP + lane]
          + b[lane];

  float m1 = v; int i1 = lane;
#pragma unroll
  for (int off = 32; off > 0; off >>= 1) {
    float ov = __shfl_xor(m1, off, 64);
    int   oi = __shfl_xor(i1, off, 64);
    if (ov > m1 || (ov == m1 && oi < i1)) { m1 = ov; i1 = oi; }
  }
  float v2 = (lane == i1) ? -__builtin_inff() : v;
  float m2 = v2; int i2 = lane;
#pragma unroll
  for (int off = 32; off > 0; off >>= 1) {
    float ov = __shfl_xor(m2, off, 64);
    int   oi = __shfl_xor(i2, off, 64);
    if (ov > m2 || (ov == m2 && oi < i2)) { m2 = ov; i2 = oi; }
  }
  float e = __expf(v - m1);
#pragma unroll
  for (int off = 32; off > 0; off >>= 1) e += __shfl_xor(e, off, 64);

  if (lane == 0) {
    out[(size_t)t * 2 + 0] = (float)i1;
    out[(size_t)t * 2 + 1] = (float)i2;
    float inv = 1.0f / e;
    out[(size_t)TOKENS * 2 + (size_t)t * 2 + 0] = inv;
    out[(size_t)TOKENS * 2 + (size_t)t * 2 + 1] = __expf(m2 - m1) * inv;
  }
}

extern "C" void kernel_launch(void* const* d_in, const int* in_sizes, int n_in,
                              void* d_out, int out_size, void* d_ws, size_t ws_size,
                              hipStream_t stream) {
  const float* x = (const float*)d_in[0];
  const float* W = (const float*)d_in[1];
  const float* b = (const float*)d_in[2];
  float* out = (float*)d_out;

  uint4* wh   = (uint4*)d_ws;                       // 32768 slots * 16B = 512 KB
  uint4* wl   = wh + 32768;                         // 512 KB
  float* part = (float*)(wl + 32768);               // 2*16384*64*4 = 8 MB

  hipLaunchKernelGGL(prep_W,    dim3(128),        dim3(256), 0, stream, W, wh, wl);
  hipLaunchKernelGGL(gemm_mfma, dim3(512 * KSPLIT), dim3(64), 0, stream, x, wh, wl, part);
  hipLaunchKernelGGL(topk_softmax, dim3(TOKENS / 4), dim3(256), 0, stream, part, b, out);
}

// Round 2
// 83.136 us; speedup vs baseline: 2.0655x; 1.1570x over previous
//
#include <hip/hip_runtime.h>
#include <hip/hip_bf16.h>
#include <cstdint>
#include <cstddef>

#define TOKENS 16384
#define DMODEL 4096
#define NEXP   64
#define NWAVE  4                      // waves per block = K-split within block
#define KSPAN  (DMODEL / NWAVE)       // 1024 k per wave
#define NKC    (KSPAN / 16)           // 64 k-chunks of 16

typedef __attribute__((ext_vector_type(8)))  short bf16x8;   // 8 bf16 = 4 VGPRs
typedef __attribute__((ext_vector_type(16))) float f32x16;   // 32x32 acc

// 8 fp32 -> hi/lo bf16 fragments (RNE hi, exact fp32 residual -> lo; ~2^-17 rel)
__device__ __forceinline__ void cvt_hilo8(const float f[8], bf16x8* hi, bf16x8* lo) {
  union { __hip_bfloat16 b; unsigned short u; } cv;
  bf16x8 hv, lv;
#pragma unroll
  for (int j = 0; j < 8; ++j) {
    __hip_bfloat16 hb = __float2bfloat16(f[j]);
    cv.b = hb; hv[j] = (short)cv.u;
    float r = f[j] - __bfloat162float(hb);          // exact
    cv.b = __float2bfloat16(r); lv[j] = (short)cv.u;
  }
  *hi = hv; *lo = lv;
}

// ---------------- kernel 1: W -> pre-fragmented bf16 hi/lo ----------------
// slot[(kc*2+et)*64 + l] (16B) = bf16 of W[et*32 + (l&31)][kc*16 + (l>>5)*8 + j], j=0..7
__global__ __launch_bounds__(256)
void prep_W(const float* __restrict__ W, uint4* __restrict__ wh, uint4* __restrict__ wl) {
  const int tid = blockIdx.x * 256 + threadIdx.x;   // 32768 threads total
  const int l  = tid & 63;
  const int et = (tid >> 6) & 1;
  const int kc = tid >> 7;                           // 0..255
  const int e  = et * 32 + (l & 31);
  const int k  = kc * 16 + (l >> 5) * 8;
  const float* src = W + (size_t)e * DMODEL + k;
  float f[8];
#pragma unroll
  for (int j = 0; j < 8; ++j) f[j] = src[j];
  bf16x8 hi, lo;
  cvt_hilo8(f, &hi, &lo);
  const int slot = (kc * 2 + et) * 64 + l;
  wh[slot] = __builtin_bit_cast(uint4, hi);
  wl[slot] = __builtin_bit_cast(uint4, lo);
}

// ---------------- kernel 2: fused MFMA GEMM + reduce + bias + top-2 + softmax ----------------
// grid 512 blocks x 256 thr. Block = 32 tokens x 64 experts; wave w does K-quarter w.
__global__ __launch_bounds__(256, 2)
void gemm_topk(const float* __restrict__ x, const uint4* __restrict__ wh,
               const uint4* __restrict__ wl, const float* __restrict__ b,
               float* __restrict__ out) {
  __shared__ float red[NWAVE][32 * NEXP];   // 32 KB

  const int tid = threadIdx.x;
  const int l   = tid & 63;
  const int w   = tid >> 6;                 // wave id = K-quarter
  const int t0  = blockIdx.x * 32;
  const int row = l & 31, g = l >> 5;

  const float* xp  = x  + (size_t)(t0 + row) * DMODEL + w * KSPAN + g * 8;
  const uint4* whp = wh + (size_t)w * (NKC * 128) + l;   // 128 uint4 per kc (2 et-tiles)
  const uint4* wlp = wl + (size_t)w * (NKC * 128) + l;

  f32x16 acc0, acc1;
#pragma unroll
  for (int i = 0; i < 16; ++i) { acc0[i] = 0.f; acc1[i] = 0.f; }

  // prefetch iter 0
  float4 a0 = *(const float4*)(xp);
  float4 a1 = *(const float4*)(xp + 4);
  uint4 bh0 = whp[0], bh1 = whp[64];
  uint4 bl0 = wlp[0], bl1 = wlp[64];

  for (int kc = 0; kc < NKC; ++kc) {
    float4 na0 = a0, na1 = a1; uint4 nh0 = bh0, nh1 = bh1, nl0 = bl0, nl1 = bl1;
    if (kc + 1 < NKC) {                      // 1-deep prefetch
      const float* xn = xp + (kc + 1) * 16;
      na0 = *(const float4*)(xn);
      na1 = *(const float4*)(xn + 4);
      const uint4* whn = whp + (kc + 1) * 128;
      const uint4* wln = wlp + (kc + 1) * 128;
      nh0 = whn[0]; nh1 = whn[64];
      nl0 = wln[0]; nl1 = wln[64];
    }
    float f[8] = {a0.x, a0.y, a0.z, a0.w, a1.x, a1.y, a1.z, a1.w};
    bf16x8 ah, al;
    cvt_hilo8(f, &ah, &al);
    bf16x8 vh0 = __builtin_bit_cast(bf16x8, bh0);
    bf16x8 vh1 = __builtin_bit_cast(bf16x8, bh1);
    bf16x8 vl0 = __builtin_bit_cast(bf16x8, bl0);
    bf16x8 vl1 = __builtin_bit_cast(bf16x8, bl1);
    // fp32-emulated: hi*hi + hi*lo + lo*hi (lo*lo ~2^-18, dropped)
    acc0 = __builtin_amdgcn_mfma_f32_32x32x16_bf16(ah, vh0, acc0, 0, 0, 0);
    acc1 = __builtin_amdgcn_mfma_f32_32x32x16_bf16(ah, vh1, acc1, 0, 0, 0);
    acc0 = __builtin_amdgcn_mfma_f32_32x32x16_bf16(ah, vl0, acc0, 0, 0, 0);
    acc1 = __builtin_amdgcn_mfma_f32_32x32x16_bf16(ah, vl1, acc1, 0, 0, 0);
    acc0 = __builtin_amdgcn_mfma_f32_32x32x16_bf16(al, vh0, acc0, 0, 0, 0);
    acc1 = __builtin_amdgcn_mfma_f32_32x32x16_bf16(al, vh1, acc1, 0, 0, 0);
    a0 = na0; a1 = na1; bh0 = nh0; bh1 = nh1; bl0 = nl0; bl1 = nl1;
  }

  // dump partial tile to this wave's LDS slab.
  // C/D layout (m74/m101): expert col = lane&31, token row = (r&3)+8*(r>>2)+4*(lane>>5)
  {
    float* rp = &red[w][0];
#pragma unroll
    for (int r = 0; r < 16; ++r) {
      const int rr = (r & 3) + 8 * (r >> 2) + 4 * g;
      rp[rr * NEXP + row]      = acc0[r];   // banks: col%32, 2-way -> free
      rp[rr * NEXP + 32 + row] = acc1[r];
    }
  }
  __syncthreads();

  // reduce 4 K-quarters + bias. thread owns elements f = tid + 256*j (col-major
  // walk: bank = tid%32, conflict-free). expert index of every f is tid&63.
  const float bias = b[tid & 63];
#pragma unroll
  for (int j = 0; j < 8; ++j) {
    const int f = tid + 256 * j;
    float s = red[0][f] + red[1][f] + red[2][f] + red[3][f] + bias;
    red[0][f] = s;                           // owner-exclusive, no race
  }
  __syncthreads();

  // top-2 + softmax: wave w handles tokens w*8 .. w*8+7, lane = expert
#pragma unroll
  for (int i = 0; i < 8; ++i) {
    const int tl = w * 8 + i;
    const float v = red[0][tl * NEXP + l];

    float m1 = v; int i1 = l;
#pragma unroll
    for (int off = 32; off > 0; off >>= 1) {
      float ov = __shfl_xor(m1, off, 64);
      int   oi = __shfl_xor(i1, off, 64);
      if (ov > m1 || (ov == m1 && oi < i1)) { m1 = ov; i1 = oi; }
    }
    float v2 = (l == i1) ? -__builtin_inff() : v;
    float m2 = v2; int i2 = l;
#pragma unroll
    for (int off = 32; off > 0; off >>= 1) {
      float ov = __shfl_xor(m2, off, 64);
      int   oi = __shfl_xor(i2, off, 64);
      if (ov > m2 || (ov == m2 && oi < i2)) { m2 = ov; i2 = oi; }
    }
    float e = __expf(v - m1);
#pragma unroll
    for (int off = 32; off > 0; off >>= 1) e += __shfl_xor(e, off, 64);

    if (l == 0) {
      const int t = t0 + tl;
      out[(size_t)t * 2 + 0] = (float)i1;
      out[(size_t)t * 2 + 1] = (float)i2;
      float inv = 1.0f / e;
      out[(size_t)TOKENS * 2 + (size_t)t * 2 + 0] = inv;
      out[(size_t)TOKENS * 2 + (size_t)t * 2 + 1] = __expf(m2 - m1) * inv;
    }
  }
}

extern "C" void kernel_launch(void* const* d_in, const int* in_sizes, int n_in,
                              void* d_out, int out_size, void* d_ws, size_t ws_size,
                              hipStream_t stream) {
  const float* x = (const float*)d_in[0];
  const float* W = (const float*)d_in[1];
  const float* b = (const float*)d_in[2];
  float* out = (float*)d_out;

  uint4* wh = (uint4*)d_ws;          // 32768 slots * 16B = 512 KB
  uint4* wl = wh + 32768;            // 512 KB

  hipLaunchKernelGGL(prep_W,    dim3(128),        dim3(256), 0, stream, W, wh, wl);
  hipLaunchKernelGGL(gemm_topk, dim3(TOKENS / 32), dim3(256), 0, stream, x, wh, wl, b, out);
}

// Round 3
// 82.239 us; speedup vs baseline: 2.0881x; 1.0109x over previous
//
#include <hip/hip_runtime.h>
#include <hip/hip_bf16.h>
#include <cstdint>
#include <cstddef>

#define TOKENS 16384
#define DMODEL 4096
#define NEXP   64
#define NWAVE  8                      // waves per block = K-split within block
#define KSPAN  (DMODEL / NWAVE)       // 512 k per wave
#define NKC    (KSPAN / 16)           // 32 k-chunks of 16

typedef __attribute__((ext_vector_type(8)))  short bf16x8;   // 8 bf16 = 4 VGPRs
typedef __attribute__((ext_vector_type(16))) float f32x16;   // 32x32 acc

// 8 fp32 -> hi/lo bf16 fragments (RNE hi, exact fp32 residual -> lo; ~2^-17 rel)
__device__ __forceinline__ void cvt_hilo8(const float f[8], bf16x8* hi, bf16x8* lo) {
  union { __hip_bfloat16 b; unsigned short u; } cv;
  bf16x8 hv, lv;
#pragma unroll
  for (int j = 0; j < 8; ++j) {
    __hip_bfloat16 hb = __float2bfloat16(f[j]);
    cv.b = hb; hv[j] = (short)cv.u;
    float r = f[j] - __bfloat162float(hb);          // exact
    cv.b = __float2bfloat16(r); lv[j] = (short)cv.u;
  }
  *hi = hv; *lo = lv;
}

// ---------------- kernel 1: W -> pre-fragmented bf16 hi/lo ----------------
// slot[(kc*2+et)*64 + l] (16B) = bf16 of W[et*32 + (l&31)][kc*16 + (l>>5)*8 + j], j=0..7
__global__ __launch_bounds__(256)
void prep_W(const float* __restrict__ W, uint4* __restrict__ wh, uint4* __restrict__ wl) {
  const int tid = blockIdx.x * 256 + threadIdx.x;   // 32768 threads total
  const int l  = tid & 63;
  const int et = (tid >> 6) & 1;
  const int kc = tid >> 7;                           // 0..255 (global k-chunk)
  const int e  = et * 32 + (l & 31);
  const int k  = kc * 16 + (l >> 5) * 8;
  const float* src = W + (size_t)e * DMODEL + k;
  float f[8];
#pragma unroll
  for (int j = 0; j < 8; ++j) f[j] = src[j];
  bf16x8 hi, lo;
  cvt_hilo8(f, &hi, &lo);
  const int slot = (kc * 2 + et) * 64 + l;
  wh[slot] = __builtin_bit_cast(uint4, hi);
  wl[slot] = __builtin_bit_cast(uint4, lo);
}

// ---------------- kernel 2: fused MFMA GEMM + reduce + bias + top-2 + softmax ----------------
// grid 512 blocks x 512 thr (8 waves). Block = 32 tokens x 64 experts; wave w does K-eighth w.
// 512 blocks = 2/CU exactly; 4096 waves = 4/SIMD.
__global__ __launch_bounds__(512, 4)
void gemm_topk(const float* __restrict__ x, const uint4* __restrict__ wh,
               const uint4* __restrict__ wl, const float* __restrict__ b,
               float* __restrict__ out) {
  __shared__ float red[NWAVE][32 * NEXP];   // 64 KB

  const int tid = threadIdx.x;
  const int l   = tid & 63;
  const int w   = tid >> 6;                 // wave id = K-eighth
  const int t0  = blockIdx.x * 32;
  const int row = l & 31, g = l >> 5;

  const float* xp  = x  + (size_t)(t0 + row) * DMODEL + w * KSPAN + g * 8;
  const uint4* whp = wh + (size_t)w * (NKC * 128) + l;   // 128 uint4 per k-chunk
  const uint4* wlp = wl + (size_t)w * (NKC * 128) + l;

  f32x16 acc0, acc1;
#pragma unroll
  for (int i = 0; i < 16; ++i) { acc0[i] = 0.f; acc1[i] = 0.f; }

  // depth-2 rotating prefetch buffers (slot index always a literal -> stays in VGPRs)
  float4 px0[2], px1[2];
  uint4  ph0[2], ph1[2], pl0[2], pl1[2];

  auto ldx = [&](int kc, int s) {
    const float* xn = xp + kc * 16;
    px0[s] = *(const float4*)(xn);
    px1[s] = *(const float4*)(xn + 4);
  };
  auto ldw = [&](int kc, int s) {
    ph0[s] = whp[kc * 128];  ph1[s] = whp[kc * 128 + 64];
    pl0[s] = wlp[kc * 128];  pl1[s] = wlp[kc * 128 + 64];
  };

  ldx(0, 0); ldw(0, 0);
  ldx(1, 1); ldw(1, 1);

  auto step = [&](int kc, int s) {
    // copy current iter's data out of the slot, then reuse the slot for kc+2
    float4 a0 = px0[s], a1 = px1[s];
    uint4 bh0 = ph0[s], bh1 = ph1[s], bl0 = pl0[s], bl1 = pl1[s];
    if (kc + 2 < NKC) { ldx(kc + 2, s); ldw(kc + 2, s); }
    float f[8] = {a0.x, a0.y, a0.z, a0.w, a1.x, a1.y, a1.z, a1.w};
    bf16x8 ah, al;
    cvt_hilo8(f, &ah, &al);
    bf16x8 vh0 = __builtin_bit_cast(bf16x8, bh0);
    bf16x8 vh1 = __builtin_bit_cast(bf16x8, bh1);
    bf16x8 vl0 = __builtin_bit_cast(bf16x8, bl0);
    bf16x8 vl1 = __builtin_bit_cast(bf16x8, bl1);
    // fp32-emulated: hi*hi + hi*lo + lo*hi (lo*lo ~2^-18, dropped)
    acc0 = __builtin_amdgcn_mfma_f32_32x32x16_bf16(ah, vh0, acc0, 0, 0, 0);
    acc1 = __builtin_amdgcn_mfma_f32_32x32x16_bf16(ah, vh1, acc1, 0, 0, 0);
    acc0 = __builtin_amdgcn_mfma_f32_32x32x16_bf16(ah, vl0, acc0, 0, 0, 0);
    acc1 = __builtin_amdgcn_mfma_f32_32x32x16_bf16(ah, vl1, acc1, 0, 0, 0);
    acc0 = __builtin_amdgcn_mfma_f32_32x32x16_bf16(al, vh0, acc0, 0, 0, 0);
    acc1 = __builtin_amdgcn_mfma_f32_32x32x16_bf16(al, vh1, acc1, 0, 0, 0);
  };

  for (int kc = 0; kc < NKC; kc += 2) { step(kc, 0); step(kc + 1, 1); }

  // dump partial tile to this wave's LDS slab.
  // C/D layout (m74/m101): expert col = lane&31, token row = (r&3)+8*(r>>2)+4*(lane>>5)
  {
    float* rp = &red[w][0];
#pragma unroll
    for (int r = 0; r < 16; ++r) {
      const int rr = (r & 3) + 8 * (r >> 2) + 4 * g;
      rp[rr * NEXP + row]      = acc0[r];   // banks: col%32, 2-way -> free
      rp[rr * NEXP + 32 + row] = acc1[r];
    }
  }
  __syncthreads();

  // reduce 8 K-eighths + bias. thread owns f = tid + 512*j (bank = tid%32, conflict-free;
  // expert index of f is f&63 == tid&63 since 512*j is a multiple of 64)
  const float bias = b[tid & 63];
#pragma unroll
  for (int j = 0; j < 4; ++j) {
    const int f = tid + 512 * j;
    float s = red[0][f] + red[1][f] + red[2][f] + red[3][f]
            + red[4][f] + red[5][f] + red[6][f] + red[7][f] + bias;
    red[0][f] = s;                           // owner-exclusive, no race
  }
  __syncthreads();

  // top-2 + softmax: wave w handles tokens w*4 .. w*4+3, lane = expert
#pragma unroll
  for (int i = 0; i < 4; ++i) {
    const int tl = w * 4 + i;
    const float v = red[0][tl * NEXP + l];

    float m1 = v; int i1 = l;
#pragma unroll
    for (int off = 32; off > 0; off >>= 1) {
      float ov = __shfl_xor(m1, off, 64);
      int   oi = __shfl_xor(i1, off, 64);
      if (ov > m1 || (ov == m1 && oi < i1)) { m1 = ov; i1 = oi; }
    }
    float v2 = (l == i1) ? -__builtin_inff() : v;
    float m2 = v2; int i2 = l;
#pragma unroll
    for (int off = 32; off > 0; off >>= 1) {
      float ov = __shfl_xor(m2, off, 64);
      int   oi = __shfl_xor(i2, off, 64);
      if (ov > m2 || (ov == m2 && oi < i2)) { m2 = ov; i2 = oi; }
    }
    float e = __expf(v - m1);
#pragma unroll
    for (int off = 32; off > 0; off >>= 1) e += __shfl_xor(e, off, 64);

    if (l == 0) {
      const int t = t0 + tl;
      out[(size_t)t * 2 + 0] = (float)i1;
      out[(size_t)t * 2 + 1] = (float)i2;
      float inv = 1.0f / e;
      out[(size_t)TOKENS * 2 + (size_t)t * 2 + 0] = inv;
      out[(size_t)TOKENS * 2 + (size_t)t * 2 + 1] = __expf(m2 - m1) * inv;
    }
  }
}

extern "C" void kernel_launch(void* const* d_in, const int* in_sizes, int n_in,
                              void* d_out, int out_size, void* d_ws, size_t ws_size,
                              hipStream_t stream) {
  const float* x = (const float*)d_in[0];
  const float* W = (const float*)d_in[1];
  const float* b = (const float*)d_in[2];
  float* out = (float*)d_out;

  uint4* wh = (uint4*)d_ws;          // 32768 slots * 16B = 512 KB
  uint4* wl = wh + 32768;            // 512 KB

  hipLaunchKernelGGL(prep_W,    dim3(128),         dim3(256), 0, stream, W, wh, wl);
  hipLaunchKernelGGL(gemm_topk, dim3(TOKENS / 32), dim3(512), 0, stream, x, wh, wl, b, out);
}

// Round 4
// 77.652 us; speedup vs baseline: 2.2114x; 1.0591x over previous
//
#include <hip/hip_runtime.h>
#include <hip/hip_bf16.h>
#include <cstdint>
#include <cstddef>

#define TOKENS 16384
#define DMODEL 4096
#define NEXP   64
#define NWAVE  4                      // waves per block = K-split within block
#define KSPAN  (DMODEL / NWAVE)       // 1024 k per wave
#define NKC    (KSPAN / 16)           // 64 k-chunks of 16
#define NMAC   (NKC / 4)              // 16 macro-iters (4 chunks = 256B/row burst)

typedef __attribute__((ext_vector_type(8)))  short bf16x8;   // 8 bf16 = 4 VGPRs
typedef __attribute__((ext_vector_type(16))) float f32x16;   // 32x32 acc

// 8 fp32 -> hi/lo bf16 fragments (RNE hi, exact fp32 residual -> lo; ~2^-17 rel)
__device__ __forceinline__ void cvt_hilo8(const float f[8], bf16x8* hi, bf16x8* lo) {
  union { __hip_bfloat16 b; unsigned short u; } cv;
  bf16x8 hv, lv;
#pragma unroll
  for (int j = 0; j < 8; ++j) {
    __hip_bfloat16 hb = __float2bfloat16(f[j]);
    cv.b = hb; hv[j] = (short)cv.u;
    float r = f[j] - __bfloat162float(hb);          // exact
    cv.b = __float2bfloat16(r); lv[j] = (short)cv.u;
  }
  *hi = hv; *lo = lv;
}

// ---------------- kernel 1: W -> pre-fragmented bf16 hi/lo ----------------
// slot[(kc*2+et)*64 + l] (16B) = bf16 of W[et*32 + (l&31)][kc*16 + (l>>5)*8 + j], j=0..7
__global__ __launch_bounds__(256)
void prep_W(const float* __restrict__ W, uint4* __restrict__ wh, uint4* __restrict__ wl) {
  const int tid = blockIdx.x * 256 + threadIdx.x;   // 32768 threads total
  const int l  = tid & 63;
  const int et = (tid >> 6) & 1;
  const int kc = tid >> 7;                           // 0..255 (global k-chunk)
  const int e  = et * 32 + (l & 31);
  const int k  = kc * 16 + (l >> 5) * 8;
  const float* src = W + (size_t)e * DMODEL + k;
  float f[8];
#pragma unroll
  for (int j = 0; j < 8; ++j) f[j] = src[j];
  bf16x8 hi, lo;
  cvt_hilo8(f, &hi, &lo);
  const int slot = (kc * 2 + et) * 64 + l;
  wh[slot] = __builtin_bit_cast(uint4, hi);
  wl[slot] = __builtin_bit_cast(uint4, lo);
}

// ---------------- kernel 2: fused MFMA GEMM + reduce + bias + top-2 + softmax ----------------
// grid 512 blocks x 256 thr (4 waves). Block = 32 tokens x 64 experts; wave w does K-quarter w.
// x loads issued as 256B-per-row macro bursts (4 consecutive 64B lines -> DRAM row reuse).
__global__ __launch_bounds__(256, 2)
void gemm_topk(const float* __restrict__ x, const uint4* __restrict__ wh,
               const uint4* __restrict__ wl, const float* __restrict__ b,
               float* __restrict__ out) {
  __shared__ float red[NWAVE][32 * NEXP];   // 32 KB

  const int tid = threadIdx.x;
  const int l   = tid & 63;
  const int w   = tid >> 6;                 // wave id = K-quarter
  const int t0  = blockIdx.x * 32;
  const int row = l & 31, g = l >> 5;

  const float* xp  = x  + (size_t)(t0 + row) * DMODEL + w * KSPAN + g * 8;
  const uint4* whp = wh + (size_t)w * (NKC * 128) + l;   // 128 uint4 per k-chunk
  const uint4* wlp = wl + (size_t)w * (NKC * 128) + l;

  f32x16 acc0, acc1;
#pragma unroll
  for (int i = 0; i < 16; ++i) { acc0[i] = 0.f; acc1[i] = 0.f; }

  // x: depth-1 macro double-buffer (8 float4/slot); W: depth-2 chunk rotation.
  // All slot indices are literals at every use site (constprop through inlined lambdas).
  float4 xa[2][8];
  uint4  ph0[2], ph1[2], pl0[2], pl1[2];

  auto ldxm = [&](int kc0, int s) {          // 8 loads back-to-back: 32 rows x 256B burst
#pragma unroll
    for (int c = 0; c < 4; ++c) {
      const float* xn = xp + (size_t)(kc0 + c) * 16;
      xa[s][c * 2]     = *(const float4*)(xn);
      xa[s][c * 2 + 1] = *(const float4*)(xn + 4);
    }
  };
  auto ldw = [&](int kc, int s) {
    ph0[s] = whp[kc * 128];  ph1[s] = whp[kc * 128 + 64];
    pl0[s] = wlp[kc * 128];  pl1[s] = wlp[kc * 128 + 64];
  };

  auto chunk = [&](int kc, int xs, int c) {  // consume chunk c of x-slot xs, W-slot kc&1
    const int ws = kc & 1;
    float4 a0 = xa[xs][c * 2], a1 = xa[xs][c * 2 + 1];
    uint4 bh0 = ph0[ws], bh1 = ph1[ws], bl0 = pl0[ws], bl1 = pl1[ws];
    if (kc + 2 < NKC) ldw(kc + 2, ws);       // same parity -> same slot, freed this chunk
    float f[8] = {a0.x, a0.y, a0.z, a0.w, a1.x, a1.y, a1.z, a1.w};
    bf16x8 ah, al;
    cvt_hilo8(f, &ah, &al);
    bf16x8 vh0 = __builtin_bit_cast(bf16x8, bh0);
    bf16x8 vh1 = __builtin_bit_cast(bf16x8, bh1);
    bf16x8 vl0 = __builtin_bit_cast(bf16x8, bl0);
    bf16x8 vl1 = __builtin_bit_cast(bf16x8, bl1);
    // fp32-emulated: hi*hi + hi*lo + lo*hi (lo*lo ~2^-18, dropped)
    acc0 = __builtin_amdgcn_mfma_f32_32x32x16_bf16(ah, vh0, acc0, 0, 0, 0);
    acc1 = __builtin_amdgcn_mfma_f32_32x32x16_bf16(ah, vh1, acc1, 0, 0, 0);
    acc0 = __builtin_amdgcn_mfma_f32_32x32x16_bf16(ah, vl0, acc0, 0, 0, 0);
    acc1 = __builtin_amdgcn_mfma_f32_32x32x16_bf16(ah, vl1, acc1, 0, 0, 0);
    acc0 = __builtin_amdgcn_mfma_f32_32x32x16_bf16(al, vh0, acc0, 0, 0, 0);
    acc1 = __builtin_amdgcn_mfma_f32_32x32x16_bf16(al, vh1, acc1, 0, 0, 0);
  };

  ldxm(0, 0);
  ldw(0, 0); ldw(1, 1);

  for (int m = 0; m < NMAC; m += 2) {        // 2 macros/iter so slot ids stay literal
    if (m + 1 < NMAC) ldxm((m + 1) * 4, 1);  // next macro's burst in flight over compute
#pragma unroll
    for (int c = 0; c < 4; ++c) chunk(m * 4 + c, 0, c);
    if (m + 2 < NMAC) ldxm((m + 2) * 4, 0);
#pragma unroll
    for (int c = 0; c < 4; ++c) chunk((m + 1) * 4 + c, 1, c);
  }

  // dump partial tile to this wave's LDS slab.
  // C/D layout (m74/m101): expert col = lane&31, token row = (r&3)+8*(r>>2)+4*(lane>>5)
  {
    float* rp = &red[w][0];
#pragma unroll
    for (int r = 0; r < 16; ++r) {
      const int rr = (r & 3) + 8 * (r >> 2) + 4 * g;
      rp[rr * NEXP + row]      = acc0[r];   // banks: col%32, 2-way -> free
      rp[rr * NEXP + 32 + row] = acc1[r];
    }
  }
  __syncthreads();

  // reduce 4 K-quarters + bias. thread owns f = tid + 256*j (bank = tid%32, conflict-free;
  // expert index of f is tid&63 since 256*j is a multiple of 64)
  const float bias = b[tid & 63];
#pragma unroll
  for (int j = 0; j < 8; ++j) {
    const int f = tid + 256 * j;
    float s = red[0][f] + red[1][f] + red[2][f] + red[3][f] + bias;
    red[0][f] = s;                           // owner-exclusive, no race
  }
  __syncthreads();

  // top-2 + softmax: wave w handles tokens w*8 .. w*8+7, lane = expert
#pragma unroll
  for (int i = 0; i < 8; ++i) {
    const int tl = w * 8 + i;
    const float v = red[0][tl * NEXP + l];

    float m1 = v; int i1 = l;
#pragma unroll
    for (int off = 32; off > 0; off >>= 1) {
      float ov = __shfl_xor(m1, off, 64);
      int   oi = __shfl_xor(i1, off, 64);
      if (ov > m1 || (ov == m1 && oi < i1)) { m1 = ov; i1 = oi; }
    }
    float v2 = (l == i1) ? -__builtin_inff() : v;
    float m2 = v2; int i2 = l;
#pragma unroll
    for (int off = 32; off > 0; off >>= 1) {
      float ov = __shfl_xor(m2, off, 64);
      int   oi = __shfl_xor(i2, off, 64);
      if (ov > m2 || (ov == m2 && oi < i2)) { m2 = ov; i2 = oi; }
    }
    float e = __expf(v - m1);
#pragma unroll
    for (int off = 32; off > 0; off >>= 1) e += __shfl_xor(e, off, 64);

    if (l == 0) {
      const int t = t0 + tl;
      out[(size_t)t * 2 + 0] = (float)i1;
      out[(size_t)t * 2 + 1] = (float)i2;
      float inv = 1.0f / e;
      out[(size_t)TOKENS * 2 + (size_t)t * 2 + 0] = inv;
      out[(size_t)TOKENS * 2 + (size_t)t * 2 + 1] = __expf(m2 - m1) * inv;
    }
  }
}

extern "C" void kernel_launch(void* const* d_in, const int* in_sizes, int n_in,
                              void* d_out, int out_size, void* d_ws, size_t ws_size,
                              hipStream_t stream) {
  const float* x = (const float*)d_in[0];
  const float* W = (const float*)d_in[1];
  const float* b = (const float*)d_in[2];
  float* out = (float*)d_out;

  uint4* wh = (uint4*)d_ws;          // 32768 slots * 16B = 512 KB
  uint4* wl = wh + 32768;            // 512 KB

  hipLaunchKernelGGL(prep_W,    dim3(128),         dim3(256), 0, stream, W, wh, wl);
  hipLaunchKernelGGL(gemm_topk, dim3(TOKENS / 32), dim3(256), 0, stream, x, wh, wl, b, out);
}